// Round 5
// baseline (166.236 us; speedup 1.0000x reference)
//
#include <hip/hip_runtime.h>
#include <hip/hip_bf16.h>
#include <stdint.h>

typedef __attribute__((ext_vector_type(8))) short short8;
typedef __attribute__((ext_vector_type(4))) float f32x4;

#define BIGF 1e9f
#define NSLOT 64                 // col tiles = N/128
#define MAXM 96                  // max genuine members per pid (λ≈16, safe)

__device__ inline float blo(unsigned int u) {
    union { unsigned int i; float f; } v; v.i = u << 16; return v.f;
}
__device__ inline float bhi(unsigned int u) {
    union { unsigned int i; float f; } v; v.i = u & 0xffff0000u; return v.f;
}
__device__ inline unsigned int fkey(float s) {   // order-preserving uint encode
    unsigned int b = __float_as_uint(s);
    return (b & 0x80000000u) ? ~b : (b | 0x80000000u);
}
__device__ inline float funkey(unsigned int k) {
    unsigned int b = (k & 0x80000000u) ? (k & 0x7fffffffu) : ~k;
    return __uint_as_float(b);
}
__device__ inline void async16(const unsigned short* g, unsigned short* l) {
    __builtin_amdgcn_global_load_lds(
        (const __attribute__((address_space(1))) void*)g,
        (__attribute__((address_space(3))) void*)l, 16, 0, 0);
}
__device__ inline unsigned short f2b(float x) {
    __hip_bfloat16 h = __float2bfloat16(x);
    return *reinterpret_cast<unsigned short*>(&h);
}

// ---------------------------------------------------------------------------
// Kernel 1: L2-normalize rows (fp32), emit bf16 + gpid, init hp sentinel.
// Block 0 also zeroes the grid-reduction scratch (stream-ordered before use).
// ---------------------------------------------------------------------------
__global__ __launch_bounds__(256) void k_normalize(
    const float* __restrict__ emb, const int* __restrict__ labels,
    const int* __restrict__ pids, unsigned short* __restrict__ normed,
    int* __restrict__ gpid, float* __restrict__ hp_init,
    float* __restrict__ gred, int* __restrict__ done)
{
    if (blockIdx.x == 0 && threadIdx.x < 3) {
        if (threadIdx.x < 2) gred[threadIdx.x] = 0.f;
        else *done = 0;
    }
    int w = threadIdx.x >> 6, lane = threadIdx.x & 63;
    int row = blockIdx.x * 4 + w;
    const float4* src = (const float4*)(emb + ((size_t)row << 8));
    float4 x = src[lane];
    float ss = x.x * x.x + x.y * x.y + x.z * x.z + x.w * x.w;
    #pragma unroll
    for (int off = 32; off >= 1; off >>= 1) ss += __shfl_xor(ss, off, 64);
    float inv = 1.0f / fmaxf(sqrtf(ss), 1e-12f);
    ushort4 o;
    o.x = f2b(x.x * inv); o.y = f2b(x.y * inv);
    o.z = f2b(x.z * inv); o.w = f2b(x.w * inv);
    ((ushort4*)(normed + ((size_t)row << 8)))[lane] = o;
    if (lane == 0) {
        gpid[row] = (labels[row] == 1) ? pids[row] : -1;
        hp_init[row] = BIGF;
    }
}

// ---------------------------------------------------------------------------
// Kernel 2: hardest positive via per-pid groups. Member rows staged into LDS
// once; M^2 pair dots then read LDS only.
// ---------------------------------------------------------------------------
__global__ __launch_bounds__(256) void k_hp_pid(
    const unsigned short* __restrict__ normed, const int* __restrict__ labels,
    const int* __restrict__ pids, float* __restrict__ hp_out, int N, int D)
{
    __shared__ int list[MAXM];
    __shared__ unsigned int hp_loc[MAXM];
    __shared__ unsigned short rows[MAXM * 256];   // 48 KB
    __shared__ int cnt;
    int p = blockIdx.x;
    int t = threadIdx.x;
    if (t == 0) cnt = 0;
    __syncthreads();
    for (int j = t; j < N; j += 256)
        if (pids[j] == p && labels[j] == 1) {
            int idx = atomicAdd(&cnt, 1);
            if (idx < MAXM) list[idx] = j;
        }
    __syncthreads();
    int M = min(cnt, MAXM);
    for (int s = t; s < M; s += 256) hp_loc[s] = 0xFFFFFFFFu;
    for (int idx = t; idx < M * 32; idx += 256) {
        int mi = idx >> 5, ch = idx & 31;
        ((uint4*)&rows[mi * 256])[ch] =
            ((const uint4*)(normed + ((size_t)list[mi] << 8)))[ch];
    }
    __syncthreads();
    for (int pr = t; pr < M * M; pr += 256) {
        int i = pr / M, j = pr - i * M;
        if (i == j) continue;
        const uint4* ap = (const uint4*)&rows[i * 256];
        const uint4* bp = (const uint4*)&rows[j * 256];
        float s = 0.f;
        #pragma unroll 4
        for (int k = 0; k < 32; ++k) {
            uint4 a = ap[k], b = bp[k];
            s += blo(a.x) * blo(b.x) + bhi(a.x) * bhi(b.x);
            s += blo(a.y) * blo(b.y) + bhi(a.y) * bhi(b.y);
            s += blo(a.z) * blo(b.z) + bhi(a.z) * bhi(b.z);
            s += blo(a.w) * blo(b.w) + bhi(a.w) * bhi(b.w);
        }
        atomicMin(&hp_loc[i], fkey(s));
    }
    __syncthreads();
    for (int s = t; s < M; s += 256) {
        unsigned int key = hp_loc[s];
        hp_out[list[s]] = (key == 0xFFFFFFFFu) ? BIGF : funkey(key);
    }
}

// ---------------------------------------------------------------------------
// Kernel 3: symmetric MFMA pass. Only upper-triangle tiles (ct >= rt) run;
// each off-diagonal block reduces BOTH directions from one accumulator set
// (sim is symmetric; masks are not -> two epilogues). Diagonal blocks stage
// A only (B == A). XOR-swizzled LDS placement (conflict-free, preserved).
// Partials transposed: p[slot*N + row], each (row,slot) written once.
// ---------------------------------------------------------------------------
__global__ __launch_bounds__(256) void k_pass2(
    const unsigned short* __restrict__ normed, const int* __restrict__ pids,
    const int* __restrict__ gpid, const float* __restrict__ hp,
    float* __restrict__ p_hnall, float* __restrict__ p_mbel, int N)
{
    const int ct = blockIdx.x, rt = blockIdx.y;
    if (ct < rt) return;
    const bool diag = (ct == rt);

    __shared__ unsigned short As[2][128 * 32];
    __shared__ unsigned short Bs[2][128 * 32];
    __shared__ float hp_r[128], hp_c[128];
    __shared__ int pid_r[128], gpid_r[128], pid_c[128], gpid_c[128];
    __shared__ unsigned int red1[128], red2[128], red3[128], red4[128];

    const int t = threadIdx.x;
    const int lane = t & 63;
    const int w = t >> 6;
    const int wr = w & 1, wc = w >> 1;
    const int quad = lane >> 4, l16 = lane & 15;
    const int rbase = rt * 128, cbase = ct * 128;

    if (t < 128) {
        hp_r[t] = hp[rbase + t];
        pid_r[t] = pids[rbase + t];
        gpid_r[t] = gpid[rbase + t];
        hp_c[t] = hp[cbase + t];
        pid_c[t] = pids[cbase + t];
        gpid_c[t] = gpid[cbase + t];
        red1[t] = 0u; red2[t] = 0u; red3[t] = 0u; red4[t] = 0u;
    }

    // staging: LDS chunk cid in {t, t+256}; row = cid>>2, pos = cid&3.
    // LDS pos holds global 16B chunk c = pos ^ ((row>>1)&3).
    const int r0 = t >> 2, p0 = t & 3;
    const int c0 = p0 ^ ((r0 >> 1) & 3);
    const unsigned short* gA0 = normed + ((size_t)(rbase + r0) << 8) + c0 * 8;
    const unsigned short* gA1 = normed + ((size_t)(rbase + r0 + 64) << 8) + c0 * 8;
    const unsigned short* gB0 = normed + ((size_t)(cbase + r0) << 8) + c0 * 8;
    const unsigned short* gB1 = normed + ((size_t)(cbase + r0 + 64) << 8) + c0 * 8;

    async16(gA0, &As[0][t * 8]);
    async16(gA1, &As[0][2048 + t * 8]);
    if (!diag) {
        async16(gB0, &Bs[0][t * 8]);
        async16(gB1, &Bs[0][2048 + t * 8]);
    }

    f32x4 acc[4][4];
    #pragma unroll
    for (int mt = 0; mt < 4; ++mt)
        #pragma unroll
        for (int nt = 0; nt < 4; ++nt)
            acc[mt][nt] = (f32x4){0.f, 0.f, 0.f, 0.f};

    const int sw = (l16 >> 1) & 3;
    const int aoff = (wr * 64 + l16) * 32 + (quad ^ sw) * 8;   // + mt*512
    const int boff = (wc * 64 + l16) * 32 + (quad ^ sw) * 8;   // + nt*512

    for (int kb = 0; kb < 8; ++kb) {
        __syncthreads();
        int cur = kb & 1;
        if (kb < 7) {
            int nxt = cur ^ 1;
            int ko = (kb + 1) << 5;
            async16(gA0 + ko, &As[nxt][t * 8]);
            async16(gA1 + ko, &As[nxt][2048 + t * 8]);
            if (!diag) {
                async16(gB0 + ko, &Bs[nxt][t * 8]);
                async16(gB1 + ko, &Bs[nxt][2048 + t * 8]);
            }
        }
        const unsigned short* Bsel = diag ? &As[cur][0] : &Bs[cur][0];
        short8 af[4], bf[4];
        #pragma unroll
        for (int mt = 0; mt < 4; ++mt)
            af[mt] = *reinterpret_cast<const short8*>(&As[cur][aoff + mt * 512]);
        #pragma unroll
        for (int nt = 0; nt < 4; ++nt)
            bf[nt] = *reinterpret_cast<const short8*>(&Bsel[boff + nt * 512]);
        #pragma unroll
        for (int mt = 0; mt < 4; ++mt)
            #pragma unroll
            for (int nt = 0; nt < 4; ++nt)
                acc[mt][nt] = __builtin_amdgcn_mfma_f32_16x16x32_bf16(
                    af[mt], bf[nt], acc[mt][nt], 0, 0, 0);
    }

    // ---- normal epilogue: anchors = rows of rbase, candidates = cols ----
    // C layout: row = mt*16+quad*4+r (+wr*64), col = nt*16+l16 (+wc*64)
    int gp[4];
    #pragma unroll
    for (int nt = 0; nt < 4; ++nt) gp[nt] = gpid_c[wc * 64 + nt * 16 + l16];
    #pragma unroll
    for (int mt = 0; mt < 4; ++mt) {
        #pragma unroll
        for (int r = 0; r < 4; ++r) {
            int rl = wr * 64 + mt * 16 + quad * 4 + r;
            int prow = pid_r[rl];
            float hprow = hp_r[rl];
            float v1 = -BIGF, v2 = -BIGF;
            #pragma unroll
            for (int nt = 0; nt < 4; ++nt) {
                float s = acc[mt][nt][r];
                float tt = (prow != gp[nt]) ? s : -BIGF;
                v1 = fmaxf(v1, tt);
                float t2 = (tt < hprow) ? tt : -BIGF;
                v2 = fmaxf(v2, t2);
            }
            #pragma unroll
            for (int off = 8; off >= 1; off >>= 1) {
                v1 = fmaxf(v1, __shfl_xor(v1, off, 64));
                v2 = fmaxf(v2, __shfl_xor(v2, off, 64));
            }
            if (l16 == 0) {
                atomicMax(&red1[rl], fkey(v1));
                atomicMax(&red2[rl], fkey(v2));
            }
        }
    }

    // ---- transpose epilogue: anchors = cols of cbase, candidates = rows ----
    if (!diag) {
        int4 gr[4];
        #pragma unroll
        for (int mt = 0; mt < 4; ++mt)
            gr[mt] = *(const int4*)&gpid_r[wr * 64 + mt * 16 + quad * 4];
        #pragma unroll
        for (int nt = 0; nt < 4; ++nt) {
            int c = wc * 64 + nt * 16 + l16;
            int pc = pid_c[c];
            float hpc = hp_c[c];
            float v1 = -BIGF, v2 = -BIGF;
            #pragma unroll
            for (int mt = 0; mt < 4; ++mt) {
                const int* g = (const int*)&gr[mt];
                #pragma unroll
                for (int r = 0; r < 4; ++r) {
                    float s = acc[mt][nt][r];
                    float tt = (pc != g[r]) ? s : -BIGF;
                    v1 = fmaxf(v1, tt);
                    float t2 = (tt < hpc) ? tt : -BIGF;
                    v2 = fmaxf(v2, t2);
                }
            }
            v1 = fmaxf(v1, __shfl_xor(v1, 16, 64));
            v1 = fmaxf(v1, __shfl_xor(v1, 32, 64));
            v2 = fmaxf(v2, __shfl_xor(v2, 16, 64));
            v2 = fmaxf(v2, __shfl_xor(v2, 32, 64));
            if (quad == 0) {
                atomicMax(&red3[c], fkey(v1));
                atomicMax(&red4[c], fkey(v2));
            }
        }
    }

    __syncthreads();
    if (t < 128) {
        p_hnall[(size_t)ct * N + rbase + t] = funkey(red1[t]);
        p_mbel[(size_t)ct * N + rbase + t] = funkey(red2[t]);
        if (!diag) {
            p_hnall[(size_t)rt * N + cbase + t] = funkey(red3[t]);
            p_mbel[(size_t)rt * N + cbase + t] = funkey(red4[t]);
        }
    }
}

// ---------------------------------------------------------------------------
// Kernel 4: per-row loss + grid reduce + fused final (last-block pattern).
// hn = (mbel > hp - margin) ? mbel : hn_all   (hn_cand == hn_all identity)
// ---------------------------------------------------------------------------
__global__ __launch_bounds__(256) void k_rowloss(
    const float* __restrict__ hp, const float* __restrict__ p_hnall,
    const float* __restrict__ p_mbel, const int* __restrict__ labels,
    float* __restrict__ gred, int* __restrict__ done,
    float* __restrict__ out, int N)
{
    int i = blockIdx.x * 256 + threadIdx.x;
    float hn_all = -BIGF, mb = -BIGF;
    #pragma unroll 8
    for (int s = 0; s < NSLOT; ++s) {
        hn_all = fmaxf(hn_all, p_hnall[(size_t)s * N + i]);
        mb = fmaxf(mb, p_mbel[(size_t)s * N + i]);
    }
    float hpv = hp[i];
    bool valid = (labels[i] == 1) && (hpv < 1e8f) && (hn_all > -1e8f);
    float hn = (mb > hpv - 0.5f) ? mb : hn_all;
    float base = fmaxf(hn - hpv + 0.5f, 0.f);
    float wgt = (hpv < 0.6f || hn > 0.3f) ? 2.f : 1.f;
    float loss = base * wgt + 0.5f * (1.f - hpv) + 0.5f * fmaxf(hn + 0.2f, 0.f);
    float lsum = valid ? loss : 0.f;
    float lcnt = valid ? 1.f : 0.f;
    #pragma unroll
    for (int off = 32; off >= 1; off >>= 1) {
        lsum += __shfl_xor(lsum, off, 64);
        lcnt += __shfl_xor(lcnt, off, 64);
    }
    __shared__ float rs[4], rc[4];
    int wv = threadIdx.x >> 6, lane = threadIdx.x & 63;
    if (lane == 0) { rs[wv] = lsum; rc[wv] = lcnt; }
    __syncthreads();
    if (threadIdx.x == 0) {
        atomicAdd(&gred[0], rs[0] + rs[1] + rs[2] + rs[3]);
        atomicAdd(&gred[1], rc[0] + rc[1] + rc[2] + rc[3]);
        __threadfence();
        int old = atomicAdd(done, 1);
        if (old == (int)gridDim.x - 1) {
            float S = atomicAdd(&gred[0], 0.f);
            float C = atomicAdd(&gred[1], 0.f);
            out[0] = (C > 0.f) ? S / fmaxf(C, 1.f) : 0.f;
        }
    }
}

extern "C" void kernel_launch(void* const* d_in, const int* in_sizes, int n_in,
                              void* d_out, int out_size, void* d_ws, size_t ws_size,
                              hipStream_t stream)
{
    const float* emb = (const float*)d_in[0];
    const int* labels = (const int*)d_in[1];
    const int* pids = (const int*)d_in[2];
    float* out = (float*)d_out;
    int N = in_sizes[1];          // 8192
    int D = in_sizes[0] / N;      // 256

    char* ws = (char*)d_ws;
    unsigned short* normed = (unsigned short*)ws;  ws += (size_t)N * D * 2;  // 4 MB bf16
    int* gpid = (int*)ws;                          ws += (size_t)N * 4;
    float* hp = (float*)ws;                        ws += (size_t)N * 4;
    float* p_hnall = (float*)ws;                   ws += (size_t)N * NSLOT * 4;
    float* p_mbel = (float*)ws;                    ws += (size_t)N * NSLOT * 4;
    float* gred = (float*)ws;                      ws += 2 * 4;   // [sum, cnt]
    int* done = (int*)ws;                          ws += 4;

    k_normalize<<<N / 4, 256, 0, stream>>>(emb, labels, pids, normed, gpid, hp,
                                           gred, done);
    k_hp_pid<<<256, 256, 0, stream>>>(normed, labels, pids, hp, N, D);
    k_pass2<<<dim3(N / 128, N / 128), 256, 0, stream>>>(normed, pids, gpid, hp,
                                                        p_hnall, p_mbel, N);
    k_rowloss<<<N / 256, 256, 0, stream>>>(hp, p_hnall, p_mbel, labels,
                                           gred, done, out, N);
}

// Round 6
// 149.982 us; speedup vs baseline: 1.1084x; 1.1084x over previous
//
#include <hip/hip_runtime.h>
#include <hip/hip_bf16.h>
#include <stdint.h>

typedef __attribute__((ext_vector_type(8))) short short8;
typedef __attribute__((ext_vector_type(4))) float f32x4;

#define BIGF 1e9f
#define NSLOT 64                 // col tiles = N/128
#define MAXM 96                  // max genuine members per pid (λ≈16, safe)

__device__ inline float blo(unsigned int u) {
    union { unsigned int i; float f; } v; v.i = u << 16; return v.f;
}
__device__ inline float bhi(unsigned int u) {
    union { unsigned int i; float f; } v; v.i = u & 0xffff0000u; return v.f;
}
__device__ inline unsigned int fkey(float s) {   // order-preserving uint encode
    unsigned int b = __float_as_uint(s);
    return (b & 0x80000000u) ? ~b : (b | 0x80000000u);
}
__device__ inline float funkey(unsigned int k) {
    unsigned int b = (k & 0x80000000u) ? (k & 0x7fffffffu) : ~k;
    return __uint_as_float(b);
}
__device__ inline void async16(const unsigned short* g, unsigned short* l) {
    __builtin_amdgcn_global_load_lds(
        (const __attribute__((address_space(1))) void*)g,
        (__attribute__((address_space(3))) void*)l, 16, 0, 0);
}
__device__ inline unsigned short f2b(float x) {
    __hip_bfloat16 h = __float2bfloat16(x);
    return *reinterpret_cast<unsigned short*>(&h);
}

// ---------------------------------------------------------------------------
// Kernel 1: L2-normalize rows (fp32), emit bf16 + gpid, init hp sentinel.
// Block 0 also zeroes the grid-reduction scratch (stream-ordered before use).
// ---------------------------------------------------------------------------
__global__ __launch_bounds__(256) void k_normalize(
    const float* __restrict__ emb, const int* __restrict__ labels,
    const int* __restrict__ pids, unsigned short* __restrict__ normed,
    int* __restrict__ gpid, float* __restrict__ hp_init,
    float* __restrict__ gred, int* __restrict__ done)
{
    if (blockIdx.x == 0 && threadIdx.x < 3) {
        if (threadIdx.x < 2) gred[threadIdx.x] = 0.f;
        else *done = 0;
    }
    int w = threadIdx.x >> 6, lane = threadIdx.x & 63;
    int row = blockIdx.x * 4 + w;
    const float4* src = (const float4*)(emb + ((size_t)row << 8));
    float4 x = src[lane];
    float ss = x.x * x.x + x.y * x.y + x.z * x.z + x.w * x.w;
    #pragma unroll
    for (int off = 32; off >= 1; off >>= 1) ss += __shfl_xor(ss, off, 64);
    float inv = 1.0f / fmaxf(sqrtf(ss), 1e-12f);
    ushort4 o;
    o.x = f2b(x.x * inv); o.y = f2b(x.y * inv);
    o.z = f2b(x.z * inv); o.w = f2b(x.w * inv);
    ((ushort4*)(normed + ((size_t)row << 8)))[lane] = o;
    if (lane == 0) {
        gpid[row] = (labels[row] == 1) ? pids[row] : -1;
        hp_init[row] = BIGF;
    }
}

// ---------------------------------------------------------------------------
// Kernel 2: hardest positive via per-pid groups. Member rows staged into LDS
// once; M^2 pair dots then read LDS only.
// ---------------------------------------------------------------------------
__global__ __launch_bounds__(256) void k_hp_pid(
    const unsigned short* __restrict__ normed, const int* __restrict__ labels,
    const int* __restrict__ pids, float* __restrict__ hp_out, int N, int D)
{
    __shared__ int list[MAXM];
    __shared__ unsigned int hp_loc[MAXM];
    __shared__ unsigned short rows[MAXM * 256];   // 48 KB
    __shared__ int cnt;
    int p = blockIdx.x;
    int t = threadIdx.x;
    if (t == 0) cnt = 0;
    __syncthreads();
    for (int j = t; j < N; j += 256)
        if (pids[j] == p && labels[j] == 1) {
            int idx = atomicAdd(&cnt, 1);
            if (idx < MAXM) list[idx] = j;
        }
    __syncthreads();
    int M = min(cnt, MAXM);
    for (int s = t; s < M; s += 256) hp_loc[s] = 0xFFFFFFFFu;
    for (int idx = t; idx < M * 32; idx += 256) {
        int mi = idx >> 5, ch = idx & 31;
        ((uint4*)&rows[mi * 256])[ch] =
            ((const uint4*)(normed + ((size_t)list[mi] << 8)))[ch];
    }
    __syncthreads();
    for (int pr = t; pr < M * M; pr += 256) {
        int i = pr / M, j = pr - i * M;
        if (i == j) continue;
        const uint4* ap = (const uint4*)&rows[i * 256];
        const uint4* bp = (const uint4*)&rows[j * 256];
        float s = 0.f;
        #pragma unroll 4
        for (int k = 0; k < 32; ++k) {
            uint4 a = ap[k], b = bp[k];
            s += blo(a.x) * blo(b.x) + bhi(a.x) * bhi(b.x);
            s += blo(a.y) * blo(b.y) + bhi(a.y) * bhi(b.y);
            s += blo(a.z) * blo(b.z) + bhi(a.z) * bhi(b.z);
            s += blo(a.w) * blo(b.w) + bhi(a.w) * bhi(b.w);
        }
        atomicMin(&hp_loc[i], fkey(s));
    }
    __syncthreads();
    for (int s = t; s < M; s += 256) {
        unsigned int key = hp_loc[s];
        hp_out[list[s]] = (key == 0xFFFFFFFFu) ? BIGF : funkey(key);
    }
}

// ---------------------------------------------------------------------------
// Kernel 3: symmetric MFMA pass, EXACT triangular launch (2080 blocks, 1-D).
// Linear block b -> (rt, ct), ct >= rt: uniform real work per block, no
// empty dispatches, machine fills to the LDS-limited 4 blocks/CU.
// Off-diagonal blocks reduce BOTH directions from one accumulator set.
// Diagonal blocks stage A only (B == A). XOR-swizzled LDS (conflict-free).
// Partials transposed: p[slot*N + row], each (row,slot) written once.
// ---------------------------------------------------------------------------
__global__ __launch_bounds__(256) void k_pass2(
    const unsigned short* __restrict__ normed, const int* __restrict__ pids,
    const int* __restrict__ gpid, const float* __restrict__ hp,
    float* __restrict__ p_hnall, float* __restrict__ p_mbel, int N)
{
    // triangle decode: rows rt=0..63, row rt holds (64-rt) blocks (ct>=rt).
    // S(rt) = 64*rt - rt*(rt-1)/2 blocks precede row rt.
    const int b = blockIdx.x;
    int rt = (int)floorf((129.0f - sqrtf(16641.0f - 8.0f * (float)b)) * 0.5f);
    rt = min(rt, 63);
    while (64 * (rt + 1) - ((rt + 1) * rt) / 2 <= b) ++rt;   // fix float edge
    while (64 * rt - (rt * (rt - 1)) / 2 > b) --rt;
    const int ct = rt + (b - (64 * rt - (rt * (rt - 1)) / 2));
    const bool diag = (ct == rt);

    __shared__ unsigned short As[2][128 * 32];
    __shared__ unsigned short Bs[2][128 * 32];
    __shared__ float hp_r[128], hp_c[128];
    __shared__ int pid_r[128], gpid_r[128], pid_c[128], gpid_c[128];
    __shared__ unsigned int red1[128], red2[128], red3[128], red4[128];

    const int t = threadIdx.x;
    const int lane = t & 63;
    const int w = t >> 6;
    const int wr = w & 1, wc = w >> 1;
    const int quad = lane >> 4, l16 = lane & 15;
    const int rbase = rt * 128, cbase = ct * 128;

    if (t < 128) {
        hp_r[t] = hp[rbase + t];
        pid_r[t] = pids[rbase + t];
        gpid_r[t] = gpid[rbase + t];
        hp_c[t] = hp[cbase + t];
        pid_c[t] = pids[cbase + t];
        gpid_c[t] = gpid[cbase + t];
        red1[t] = 0u; red2[t] = 0u; red3[t] = 0u; red4[t] = 0u;
    }

    // staging: LDS chunk cid in {t, t+256}; row = cid>>2, pos = cid&3.
    // LDS pos holds global 16B chunk c = pos ^ ((row>>1)&3).
    const int r0 = t >> 2, p0 = t & 3;
    const int c0 = p0 ^ ((r0 >> 1) & 3);
    const unsigned short* gA0 = normed + ((size_t)(rbase + r0) << 8) + c0 * 8;
    const unsigned short* gA1 = normed + ((size_t)(rbase + r0 + 64) << 8) + c0 * 8;
    const unsigned short* gB0 = normed + ((size_t)(cbase + r0) << 8) + c0 * 8;
    const unsigned short* gB1 = normed + ((size_t)(cbase + r0 + 64) << 8) + c0 * 8;

    async16(gA0, &As[0][t * 8]);
    async16(gA1, &As[0][2048 + t * 8]);
    if (!diag) {
        async16(gB0, &Bs[0][t * 8]);
        async16(gB1, &Bs[0][2048 + t * 8]);
    }

    f32x4 acc[4][4];
    #pragma unroll
    for (int mt = 0; mt < 4; ++mt)
        #pragma unroll
        for (int nt = 0; nt < 4; ++nt)
            acc[mt][nt] = (f32x4){0.f, 0.f, 0.f, 0.f};

    const int sw = (l16 >> 1) & 3;
    const int aoff = (wr * 64 + l16) * 32 + (quad ^ sw) * 8;   // + mt*512
    const int boff = (wc * 64 + l16) * 32 + (quad ^ sw) * 8;   // + nt*512

    // hoisted B-select (diag reads B fragments from As)
    const unsigned short* Bbase[2] = { diag ? &As[0][0] : &Bs[0][0],
                                       diag ? &As[1][0] : &Bs[1][0] };

    for (int kb = 0; kb < 8; ++kb) {
        __syncthreads();
        int cur = kb & 1;
        if (kb < 7) {
            int nxt = cur ^ 1;
            int ko = (kb + 1) << 5;
            async16(gA0 + ko, &As[nxt][t * 8]);
            async16(gA1 + ko, &As[nxt][2048 + t * 8]);
            if (!diag) {
                async16(gB0 + ko, &Bs[nxt][t * 8]);
                async16(gB1 + ko, &Bs[nxt][2048 + t * 8]);
            }
        }
        short8 af[4], bf[4];
        #pragma unroll
        for (int mt = 0; mt < 4; ++mt)
            af[mt] = *reinterpret_cast<const short8*>(&As[cur][aoff + mt * 512]);
        #pragma unroll
        for (int nt = 0; nt < 4; ++nt)
            bf[nt] = *reinterpret_cast<const short8*>(&Bbase[cur][boff + nt * 512]);
        #pragma unroll
        for (int mt = 0; mt < 4; ++mt)
            #pragma unroll
            for (int nt = 0; nt < 4; ++nt)
                acc[mt][nt] = __builtin_amdgcn_mfma_f32_16x16x32_bf16(
                    af[mt], bf[nt], acc[mt][nt], 0, 0, 0);
    }

    // ---- normal epilogue: anchors = rows of rbase, candidates = cols ----
    // C layout: row = mt*16+quad*4+r (+wr*64), col = nt*16+l16 (+wc*64)
    int gp[4];
    #pragma unroll
    for (int nt = 0; nt < 4; ++nt) gp[nt] = gpid_c[wc * 64 + nt * 16 + l16];
    #pragma unroll
    for (int mt = 0; mt < 4; ++mt) {
        #pragma unroll
        for (int r = 0; r < 4; ++r) {
            int rl = wr * 64 + mt * 16 + quad * 4 + r;
            int prow = pid_r[rl];
            float hprow = hp_r[rl];
            float v1 = -BIGF, v2 = -BIGF;
            #pragma unroll
            for (int nt = 0; nt < 4; ++nt) {
                float s = acc[mt][nt][r];
                float tt = (prow != gp[nt]) ? s : -BIGF;
                v1 = fmaxf(v1, tt);
                float t2 = (tt < hprow) ? tt : -BIGF;
                v2 = fmaxf(v2, t2);
            }
            #pragma unroll
            for (int off = 8; off >= 1; off >>= 1) {
                v1 = fmaxf(v1, __shfl_xor(v1, off, 64));
                v2 = fmaxf(v2, __shfl_xor(v2, off, 64));
            }
            if (l16 == 0) {
                atomicMax(&red1[rl], fkey(v1));
                atomicMax(&red2[rl], fkey(v2));
            }
        }
    }

    // ---- transpose epilogue: anchors = cols of cbase, candidates = rows ----
    if (!diag) {
        int4 gr[4];
        #pragma unroll
        for (int mt = 0; mt < 4; ++mt)
            gr[mt] = *(const int4*)&gpid_r[wr * 64 + mt * 16 + quad * 4];
        #pragma unroll
        for (int nt = 0; nt < 4; ++nt) {
            int c = wc * 64 + nt * 16 + l16;
            int pc = pid_c[c];
            float hpc = hp_c[c];
            float v1 = -BIGF, v2 = -BIGF;
            #pragma unroll
            for (int mt = 0; mt < 4; ++mt) {
                const int* g = (const int*)&gr[mt];
                #pragma unroll
                for (int r = 0; r < 4; ++r) {
                    float s = acc[mt][nt][r];
                    float tt = (pc != g[r]) ? s : -BIGF;
                    v1 = fmaxf(v1, tt);
                    float t2 = (tt < hpc) ? tt : -BIGF;
                    v2 = fmaxf(v2, t2);
                }
            }
            v1 = fmaxf(v1, __shfl_xor(v1, 16, 64));
            v1 = fmaxf(v1, __shfl_xor(v1, 32, 64));
            v2 = fmaxf(v2, __shfl_xor(v2, 16, 64));
            v2 = fmaxf(v2, __shfl_xor(v2, 32, 64));
            if (quad == 0) {
                atomicMax(&red3[c], fkey(v1));
                atomicMax(&red4[c], fkey(v2));
            }
        }
    }

    __syncthreads();
    if (t < 128) {
        p_hnall[(size_t)ct * N + rbase + t] = funkey(red1[t]);
        p_mbel[(size_t)ct * N + rbase + t] = funkey(red2[t]);
        if (!diag) {
            p_hnall[(size_t)rt * N + cbase + t] = funkey(red3[t]);
            p_mbel[(size_t)rt * N + cbase + t] = funkey(red4[t]);
        }
    }
}

// ---------------------------------------------------------------------------
// Kernel 4: per-row loss + grid reduce + fused final (last-block pattern).
// hn = (mbel > hp - margin) ? mbel : hn_all   (hn_cand == hn_all identity)
// ---------------------------------------------------------------------------
__global__ __launch_bounds__(256) void k_rowloss(
    const float* __restrict__ hp, const float* __restrict__ p_hnall,
    const float* __restrict__ p_mbel, const int* __restrict__ labels,
    float* __restrict__ gred, int* __restrict__ done,
    float* __restrict__ out, int N)
{
    int i = blockIdx.x * 256 + threadIdx.x;
    float hn_all = -BIGF, mb = -BIGF;
    #pragma unroll 8
    for (int s = 0; s < NSLOT; ++s) {
        hn_all = fmaxf(hn_all, p_hnall[(size_t)s * N + i]);
        mb = fmaxf(mb, p_mbel[(size_t)s * N + i]);
    }
    float hpv = hp[i];
    bool valid = (labels[i] == 1) && (hpv < 1e8f) && (hn_all > -1e8f);
    float hn = (mb > hpv - 0.5f) ? mb : hn_all;
    float base = fmaxf(hn - hpv + 0.5f, 0.f);
    float wgt = (hpv < 0.6f || hn > 0.3f) ? 2.f : 1.f;
    float loss = base * wgt + 0.5f * (1.f - hpv) + 0.5f * fmaxf(hn + 0.2f, 0.f);
    float lsum = valid ? loss : 0.f;
    float lcnt = valid ? 1.f : 0.f;
    #pragma unroll
    for (int off = 32; off >= 1; off >>= 1) {
        lsum += __shfl_xor(lsum, off, 64);
        lcnt += __shfl_xor(lcnt, off, 64);
    }
    __shared__ float rs[4], rc[4];
    int wv = threadIdx.x >> 6, lane = threadIdx.x & 63;
    if (lane == 0) { rs[wv] = lsum; rc[wv] = lcnt; }
    __syncthreads();
    if (threadIdx.x == 0) {
        atomicAdd(&gred[0], rs[0] + rs[1] + rs[2] + rs[3]);
        atomicAdd(&gred[1], rc[0] + rc[1] + rc[2] + rc[3]);
        __threadfence();
        int old = atomicAdd(done, 1);
        if (old == (int)gridDim.x - 1) {
            float S = atomicAdd(&gred[0], 0.f);
            float C = atomicAdd(&gred[1], 0.f);
            out[0] = (C > 0.f) ? S / fmaxf(C, 1.f) : 0.f;
        }
    }
}

extern "C" void kernel_launch(void* const* d_in, const int* in_sizes, int n_in,
                              void* d_out, int out_size, void* d_ws, size_t ws_size,
                              hipStream_t stream)
{
    const float* emb = (const float*)d_in[0];
    const int* labels = (const int*)d_in[1];
    const int* pids = (const int*)d_in[2];
    float* out = (float*)d_out;
    int N = in_sizes[1];          // 8192
    int D = in_sizes[0] / N;      // 256

    char* ws = (char*)d_ws;
    unsigned short* normed = (unsigned short*)ws;  ws += (size_t)N * D * 2;  // 4 MB bf16
    int* gpid = (int*)ws;                          ws += (size_t)N * 4;
    float* hp = (float*)ws;                        ws += (size_t)N * 4;
    float* p_hnall = (float*)ws;                   ws += (size_t)N * NSLOT * 4;
    float* p_mbel = (float*)ws;                    ws += (size_t)N * NSLOT * 4;
    float* gred = (float*)ws;                      ws += 2 * 4;   // [sum, cnt]
    int* done = (int*)ws;                          ws += 4;

    int M = N / 128;                         // 64 tiles
    int tri = M * (M + 1) / 2;               // 2080 blocks

    k_normalize<<<N / 4, 256, 0, stream>>>(emb, labels, pids, normed, gpid, hp,
                                           gred, done);
    k_hp_pid<<<256, 256, 0, stream>>>(normed, labels, pids, hp, N, D);
    k_pass2<<<tri, 256, 0, stream>>>(normed, pids, gpid, hp,
                                     p_hnall, p_mbel, N);
    k_rowloss<<<N / 256, 256, 0, stream>>>(hp, p_hnall, p_mbel, labels,
                                           gred, done, out, N);
}